// Round 15
// baseline (1893.636 us; speedup 1.0000x reference)
//
#include <hip/hip_runtime.h>

// ---------------------------------------------------------------------------
// RNN (LSTM) + CRF loss on MI355X — round 15.
// Batch-independent decomposition: 8 groups x 8 batches; group = 16 lstm
// blocks (4 waves x 8 u each) -> exchange only within group (8KB/step).
// Flags: dual-published — sc1 (always correct, r13 semantics) + epoch-rotated
// plain flags (L2-visible when group co-locates on one XCD; monotone values
// -> stale reads can never false-positive; bounded fast-poll falls back to
// the unbounded sc1 poll). h data: sc1 stores + plain unique-address loads
// (r13-proven). CRF blocks (64) fold the emissions matvec in-block (em
// buffer/role deleted). Grid: 128 lstm + 64 crf = 192 blocks x 256 thr.
// ---------------------------------------------------------------------------

typedef float f32x4 __attribute__((ext_vector_type(4)));
typedef __bf16 bf16x8 __attribute__((ext_vector_type(8)));
typedef unsigned int u32x4 __attribute__((ext_vector_type(4)));

#define T_LEN 256
#define BB    64
#define EE    256
#define HH    512
#define KK    128
#define KCAT  768   // E + H

static __device__ inline unsigned f2bf(float f) {
  union { float f; unsigned u; } v; v.f = f;
  unsigned r = v.u + 0x7FFF + ((v.u >> 16) & 1);   // round-nearest-even
  return r >> 16;
}
static __device__ inline float bf2f(unsigned short u) {
  union { unsigned u; float f; } v; v.u = ((unsigned)u) << 16;
  return v.f;
}
static __device__ inline float sigm(float x) { return 1.f / (1.f + __expf(-x)); }
static __device__ inline float tanh_fast(float x) {
  return 1.f - 2.f / (1.f + __expf(2.f * x));      // safe at +/-inf
}
static __device__ inline bf16x8 ubf(u32x4 v) {
  union { u32x4 u; bf16x8 b; } c; c.u = v; return c.b;
}

// --- 1. weight conversion (LDS tile transpose, coalesced both sides) -------
__global__ __launch_bounds__(256) void build_wcat(
    const float* __restrict__ Wi, const float* __restrict__ Wh,
    unsigned short* __restrict__ WcatT) {
  __shared__ float tile[64][65];
  int ct = blockIdx.x & 31, kt = blockIdx.x >> 5;    // 32 c-tiles x 12 k-tiles
  int tc = threadIdx.x & 63, tr = threadIdx.x >> 6;
  int c0 = ct * 64, k0 = kt * 64;
#pragma unroll
  for (int i = 0; i < 16; ++i) {
    int r = tr * 16 + i, k = k0 + r;
    float v = (k < EE) ? Wi[(size_t)k * 2048 + c0 + tc]
                       : Wh[(size_t)(k - EE) * 2048 + c0 + tc];
    tile[r][tc] = v;
  }
  __syncthreads();
#pragma unroll
  for (int i = 0; i < 16; ++i) {
    int cL = tr * 16 + i;
    WcatT[(size_t)(c0 + cL) * KCAT + k0 + tc] = (unsigned short)f2bf(tile[tc][cL]);
  }
}

__global__ __launch_bounds__(256) void build_wout(
    const float* __restrict__ Wout, unsigned short* __restrict__ WoutT) {
  __shared__ float tile[64][65];
  int ct = blockIdx.x & 1, kt = blockIdx.x >> 1;     // 2 c-tiles x 8 k-tiles
  int tc = threadIdx.x & 63, tr = threadIdx.x >> 6;
  int c0 = ct * 64, k0 = kt * 64;
#pragma unroll
  for (int i = 0; i < 16; ++i) {
    int r = tr * 16 + i;
    tile[r][tc] = Wout[(size_t)(k0 + r) * KK + c0 + tc];
  }
  __syncthreads();
#pragma unroll
  for (int i = 0; i < 16; ++i) {
    int cL = tr * 16 + i;
    WoutT[(size_t)(c0 + cL) * HH + k0 + tc] = (unsigned short)f2bf(tile[tc][cL]);
  }
}

// --- 2. embedding ----------------------------------------------------------
__global__ __launch_bounds__(256) void embed_kernel(
    const int* __restrict__ wx, const int* __restrict__ cx,
    const float* __restrict__ we, const float* __restrict__ ce,
    unsigned short* __restrict__ x) {
  int bid = blockIdx.x;             // t*64 + b
  int t = bid >> 6, b = bid & 63;
  int e = threadIdx.x;              // 0..255
  int w = wx[b * T_LEN + t];
  float v = we[(size_t)w * EE + e];
  const int* cp = cx + ((size_t)(b * T_LEN + t)) * 8;
  float s = 0.f;
#pragma unroll
  for (int l = 0; l < 8; ++l) s += ce[(size_t)cp[l] * EE + e];
  v += s * 0.125f;
  x[(size_t)bid * EE + e] = (unsigned short)f2bf(v);
}

// --- 3. flag reset: flagS[128] + flagE[64][128] ------------------------------
__global__ void zero_flags(unsigned int* __restrict__ f) {
  int i = blockIdx.x * 256 + threadIdx.x;
  if (i < 128 + 64 * 128) {
    unsigned z = 0u;
    asm volatile("global_store_dword %0, %1, off sc1"
                 :: "v"(f + i), "v"(z) : "memory");
  }
}

// --- 4. fused persistent kernel ---------------------------------------------
#define SBAR __builtin_amdgcn_sched_barrier(0)
#define WAIT0 do { asm volatile("s_waitcnt vmcnt(0)" ::: "memory"); SBAR; } while (0)
#define LDN(dst, p, OFF) \
  asm volatile("global_load_dwordx4 %0, %1, off offset:" OFF \
               : "=v"(dst) : "v"(p) : "memory")

#define ISSUE_X8(B, P) do { \
  LDN(B[0],P,"0");   LDN(B[1],P,"64");  LDN(B[2],P,"128"); LDN(B[3],P,"192"); \
  LDN(B[4],P,"256"); LDN(B[5],P,"320"); LDN(B[6],P,"384"); LDN(B[7],P,"448"); } while (0)
#define ISSUE_H16(B, P) do { \
  LDN(B[0],P,"0");   LDN(B[1],P,"64");  LDN(B[2],P,"128"); LDN(B[3],P,"192"); \
  LDN(B[4],P,"256"); LDN(B[5],P,"320"); LDN(B[6],P,"384"); LDN(B[7],P,"448"); \
  LDN(B[8],P,"512"); LDN(B[9],P,"576"); LDN(B[10],P,"640"); LDN(B[11],P,"704"); \
  LDN(B[12],P,"768"); LDN(B[13],P,"832"); LDN(B[14],P,"896"); LDN(B[15],P,"960"); } while (0)

__global__ __launch_bounds__(256, 1) void fused_kernel(
    const unsigned short* __restrict__ x,      // [T][64][256] bf16
    unsigned short* __restrict__ hs,           // [256][64][512] bf16 (slot t = h[t+1])
    const unsigned short* __restrict__ WcatT,  // [2048][768] bf16
    const unsigned short* __restrict__ WoutT,  // [128][512] bf16
    const float* __restrict__ bias,            // [2048]
    const float* __restrict__ bout,            // [128]
    const float* __restrict__ trans,           // [128][128]
    const int* __restrict__ wx,                // [64][256]
    const int* __restrict__ y,                 // [64][257]
    unsigned int* __restrict__ flags,          // flagS[128] ++ flagE[64][128]
    float* __restrict__ out) {                 // [64]
  __shared__ float s_El[KK][129];              // 66 KB
  __shared__ float s_h[HH];
  __shared__ float s_p[KK];
  __shared__ float s_mv[2 * KK];
  __shared__ float s_Sp[2 * KK];
  __shared__ float s_red2[2];
  __shared__ float s_redg[256];

  const int bid = blockIdx.x;
  const int tid = threadIdx.x;
  const int wave = tid >> 6, lane = tid & 63;
  unsigned int* flagS = flags;
  unsigned int* flagE = flags + 128;

  if (bid < 128) {
    // ================= LSTM role =================
    const int g = bid & 7, usl = bid >> 3;
    const int j = lane & 15, kq = lane >> 4;
    const int u0 = usl * 32 + wave * 8;
    const int batch = g * 8 + (j < 8 ? j : 7);
    const bool jval = (j < 8);

    // 48 loop-invariant weight A-frags -> 192 VGPR
    bf16x8 wreg0[24], wreg1[24];
#pragma unroll
    for (int s = 0; s < 24; ++s) {
      int zc0 = (j & 3) * HH + u0 + 0 + (j >> 2);
      int zc1 = (j & 3) * HH + u0 + 4 + (j >> 2);
      wreg0[s] = *(const bf16x8*)(WcatT + (size_t)zc0 * KCAT + s * 32 + kq * 8);
      wreg1[s] = *(const bf16x8*)(WcatT + (size_t)zc1 * KCAT + s * 32 + kq * 8);
    }
    float bv0[4], bv1[4];
#pragma unroll
    for (int r = 0; r < 4; ++r) {
      bv0[r] = bias[r * HH + u0 + 0 + kq];
      bv1[r] = bias[r * HH + u0 + 4 + kq];
    }

    const char* xpc = (const char*)x + ((size_t)batch * EE + kq * 8) * 2;
    const char* hpc = (const char*)hs + ((size_t)batch * HH + kq * 8) * 2;
    char* hsc = (char*)hs + ((size_t)batch * HH + u0 + kq) * 2;
    const int* wxp = wx + batch * T_LEN;
    unsigned int* fSp = flagS + j * 8 + g;     // group-mate bid = j*8+g

    float cst[2] = {0.f, 0.f}, hst[2] = {0.f, 0.f};
    u32x4 xf[8], hf[16];
    unsigned wxv;
    f32x4 acc0, acc1;

    for (int t = 0; t < T_LEN; ++t) {
      ISSUE_X8(xf, (xpc + (size_t)t * 32768));
      asm volatile("global_load_dword %0, %1, off" : "=v"(wxv) : "v"(wxp + t) : "memory");
      if (t > 0) {
        // fast poll: epoch-rotated plain flags (L2 when group co-located);
        // monotone values -> no false positive; fallback: sc1 (r13, proven)
        unsigned int* fEp = flagE + (t & 63) * 128 + j * 8 + g;
        bool ok = false;
        for (int it = 0; it < 64; ++it) {
          unsigned v;
          asm volatile("global_load_dword %0, %1, off\n\ts_waitcnt vmcnt(0)"
                       : "=v"(v) : "v"(fEp) : "memory");
          if (__all((int)(v >= (unsigned)t))) { ok = true; break; }
        }
        if (!ok) {
          unsigned v;
          do {
            asm volatile("global_load_dword %0, %1, off sc1\n\ts_waitcnt vmcnt(0)"
                         : "=v"(v) : "v"(fSp) : "memory");
          } while (!__all((int)(v >= (unsigned)t)));
        }
        SBAR;
        ISSUE_H16(hf, (hpc + (size_t)(t - 1) * 65536));   // plain, unique addrs
      } else {
        WAIT0;
      }
#pragma unroll
      for (int r = 0; r < 4; ++r) { acc0[r] = bv0[r]; acc1[r] = bv1[r]; }
#pragma unroll
      for (int f = 0; f < 8; ++f) {            // x-part (drained by poll/WAIT0)
        bf16x8 d = ubf(xf[f]);
        acc0 = __builtin_amdgcn_mfma_f32_16x16x32_bf16(wreg0[f], d, acc0, 0, 0, 0);
        acc1 = __builtin_amdgcn_mfma_f32_16x16x32_bf16(wreg1[f], d, acc1, 0, 0, 0);
      }
      if (t > 0) {
        WAIT0;                                 // h frags arrived
#pragma unroll
        for (int f = 0; f < 16; ++f) {
          bf16x8 d = ubf(hf[f]);
          acc0 = __builtin_amdgcn_mfma_f32_16x16x32_bf16(wreg0[8 + f], d, acc0, 0, 0, 0);
          acc1 = __builtin_amdgcn_mfma_f32_16x16x32_bf16(wreg1[8 + f], d, acc1, 0, 0, 0);
        }
      }
      // gates: lane owns (batch, u0+kq) [tile0] and (batch, u0+4+kq) [tile1]
      bool mk = ((int)wxv) > 0;
      {
        float cn = sigm(acc0[1]) * cst[0] + sigm(acc0[0]) * tanh_fast(acc0[2]);
        float hn = sigm(acc0[3]) * tanh_fast(cn);
        if (mk) { cst[0] = cn; hst[0] = hn; }
        float cn1 = sigm(acc1[1]) * cst[1] + sigm(acc1[0]) * tanh_fast(acc1[2]);
        float hn1 = sigm(acc1[3]) * tanh_fast(cn1);
        if (mk) { cst[1] = cn1; hst[1] = hn1; }
      }
      if (jval) {
        unsigned v0 = f2bf(hst[0]), v1 = f2bf(hst[1]);
        asm volatile("global_store_short %0, %1, off sc1"
                     :: "v"(hsc + (size_t)t * 65536), "v"(v0) : "memory");
        asm volatile("global_store_short %0, %1, off offset:8 sc1"
                     :: "v"(hsc + (size_t)t * 65536), "v"(v1) : "memory");
      }
      WAIT0;                                   // h[t+1] ack'd (LLC-visible)
      __syncthreads();                         // all 4 waves drained
      if (tid == 0) {
        unsigned nv = (unsigned)(t + 1);
        asm volatile("global_store_dword %0, %1, off sc1"
                     :: "v"(flagS + bid), "v"(nv) : "memory");
        asm volatile("global_store_dword %0, %1, off"
                     :: "v"(flagE + ((t + 1) & 63) * 128 + bid), "v"(nv) : "memory");
      }
    }
  } else {
    // ================= CRF role: b = bid - 128 =================
    const int b = bid - 128;
    const int gq = b >> 3;
    const int k = tid & 127, half = tid >> 7;
    for (int i = tid; i < KK * KK; i += 256)
      s_El[i >> 7][i & 127] = __expf(trans[i]);   // exp(-1e4) = 0
    __syncthreads();

    float sck = (k == 1) ? 0.f : -10000.f;
    float msc = 0.f, gold = 0.f;
    int len = 0;
    unsigned int* fSp = flagS + (lane & 15) * 8 + gq;

    for (int t = 0; t < T_LEN; ++t) {
      if (wx[b * T_LEN + t] <= 0) continue;    // block-uniform
      {
        unsigned v; int it = 0;
        do {
          asm volatile("global_load_dword %0, %1, off sc1\n\ts_waitcnt vmcnt(0)"
                       : "=v"(v) : "v"(fSp) : "memory");
          if (__all((int)(v >= (unsigned)(t + 1)))) break;
        } while (++it < (1 << 20));            // bailout: fail visibly
        SBAR;
      }
      // stage h[t+1][b] row as f32 (plain loads: unique addrs, LLC-fresh)
      {
        unsigned hv = *(const unsigned*)(hs + ((size_t)t * BB + b) * HH + tid * 2);
        s_h[tid * 2]     = bf2f((unsigned short)(hv & 0xffff));
        s_h[tid * 2 + 1] = bf2f((unsigned short)(hv >> 16));
      }
      __syncthreads();
      // em_k = bout[k] + dot(h, Wout[:,k]) — split across halves
      float e = 0.f;
      const char* wp = (const char*)WoutT + ((size_t)k * HH + half * 256) * 2;
#pragma unroll 8
      for (int f = 0; f < 32; ++f) {
        u32x4 wv = *(const u32x4*)(wp + f * 16);
        const float* hb = s_h + half * 256 + f * 8;
#pragma unroll
        for (int d = 0; d < 4; ++d) {
          e += hb[d * 2]     * bf2f((unsigned short)(wv[d] & 0xffff));
          e += hb[d * 2 + 1] * bf2f((unsigned short)(wv[d] >> 16));
        }
      }
      s_mv[half * KK + k] = e;
      __syncthreads();
      float em_k = s_mv[k] + s_mv[KK + k] + bout[k];
      // CRF step (E-precompute, r10-proven math)
      if (tid < KK) s_p[tid] = __expf(sck - msc);
      __syncthreads();
      float S = 0.f;
#pragma unroll
      for (int jj = 0; jj < 64; ++jj) S += s_El[k][half * 64 + jj] * s_p[half * 64 + jj];
      s_Sp[half * KK + k] = S;
      __syncthreads();
      float ns = em_k + msc + __logf(s_Sp[k] + s_Sp[KK + k]);
      // gold
      int yn = y[b * 257 + t + 1];
      if (half == 0 && k == yn) gold += em_k + trans[yn * KK + y[b * 257 + t]];
      len++;
      sck = ns;
      // msc = max_k ns (waves 0,1 cover k 0..127)
      if (half == 0) {
        float m = ns;
#pragma unroll
        for (int off = 32; off; off >>= 1) m = fmaxf(m, __shfl_xor(m, off));
        if (lane == 0) s_red2[wave] = m;
      }
      __syncthreads();                         // also guards s_h/s_p/s_mv reuse
      msc = fmaxf(s_red2[0], s_red2[1]);
    }

    // block-reduce gold
    s_redg[tid] = gold;
    __syncthreads();
    for (int s2 = 128; s2 > 0; s2 >>= 1) {
      if (tid < s2) s_redg[tid] += s_redg[tid + s2];
      __syncthreads();
    }
    gold = s_redg[0];
    __syncthreads();

    // Z = LSE_k(sc[k] + trans[EOS][k])
    float v = sck + trans[2 * KK + k];
    if (half == 0) s_redg[k] = v; else s_redg[128 + k] = -3.0e38f;
    __syncthreads();
    for (int s2 = 64; s2 > 0; s2 >>= 1) {
      if (tid < s2) s_redg[tid] = fmaxf(s_redg[tid], s_redg[tid + s2]);
      __syncthreads();
    }
    float mz = s_redg[0];
    __syncthreads();
    s_redg[tid] = (half == 0) ? __expf(v - mz) : 0.f;
    __syncthreads();
    for (int s2 = 128; s2 > 0; s2 >>= 1) {
      if (tid < s2) s_redg[tid] += s_redg[tid + s2];
      __syncthreads();
    }
    if (tid == 0) {
      float Z = mz + __logf(s_redg[0]);
      int last_tag = y[b * 257 + len];
      out[b] = Z - (gold + trans[2 * KK + last_tag]);
    }
  }
}

// ---------------------------------------------------------------------------
extern "C" void kernel_launch(void* const* d_in, const int* in_sizes, int n_in,
                              void* d_out, int out_size, void* d_ws, size_t ws_size,
                              hipStream_t stream) {
  const int*   cx    = (const int*)d_in[0];
  const int*   wx    = (const int*)d_in[1];
  const int*   y     = (const int*)d_in[2];
  const float* ce    = (const float*)d_in[3];
  const float* we    = (const float*)d_in[4];
  const float* Wi    = (const float*)d_in[5];
  const float* Wh    = (const float*)d_in[6];
  const float* bias  = (const float*)d_in[7];
  const float* Wout  = (const float*)d_in[8];
  const float* bout  = (const float*)d_in[9];
  const float* trans = (const float*)d_in[10];
  float* out = (float*)d_out;

  char* ws = (char*)d_ws;
  // ws layout (16B aligned), ~28.5 MB
  unsigned short* WcatT = (unsigned short*)(ws + 0);          //  3,145,728
  unsigned short* WoutT = (unsigned short*)(ws + 3145728);    //    131,072
  unsigned short* x     = (unsigned short*)(ws + 3276800);    //  8,388,608
  unsigned short* hs    = (unsigned short*)(ws + 11665408);   // 16,777,216
  unsigned int*   flags = (unsigned int*)(ws + 28442624);     // 33,280 B

  build_wcat<<<384, 256, 0, stream>>>(Wi, Wh, WcatT);
  build_wout<<<16, 256, 0, stream>>>(Wout, WoutT);
  embed_kernel<<<T_LEN * BB, 256, 0, stream>>>(wx, cx, we, ce, x);
  zero_flags<<<33, 256, 0, stream>>>(flags);
  fused_kernel<<<192, 256, 0, stream>>>(x, hs, WcatT, WoutT, bias, bout, trans,
                                        wx, y, flags, out);
}

// Round 16
// 1437.843 us; speedup vs baseline: 1.3170x; 1.3170x over previous
//
#include <hip/hip_runtime.h>

// ---------------------------------------------------------------------------
// RNN (LSTM) + CRF loss on MI355X — round 16.
// = round 14 (best, 1463us) + s_sleep backoff in the em/crf poll loops.
// r14's em (8 blocks) + crf (64 blocks) polled sc1 flags in tight loops,
// generating continuous LLC traffic that queued against the lstm exchange's
// latency-critical round trips (+180us vs lstm-only r13). Their polls are
// slack-rich (~5us of slack per step) -> backoff costs them nothing.
// LSTM role unchanged (r13-proven: plain h loads, sc1 stores, tight poll).
// ---------------------------------------------------------------------------

typedef float f32x4 __attribute__((ext_vector_type(4)));
typedef float f32x16 __attribute__((ext_vector_type(16)));
typedef __bf16 bf16x8 __attribute__((ext_vector_type(8)));
typedef unsigned int u32x4 __attribute__((ext_vector_type(4)));
typedef unsigned int u32x2 __attribute__((ext_vector_type(2)));

#define T_LEN 256
#define BB    64
#define EE    256
#define HH    512
#define KK    128
#define KCAT  768   // E + H

static __device__ inline unsigned f2bf(float f) {
  union { float f; unsigned u; } v; v.f = f;
  unsigned r = v.u + 0x7FFF + ((v.u >> 16) & 1);   // round-nearest-even
  return r >> 16;
}
static __device__ inline float sigm(float x) { return 1.f / (1.f + __expf(-x)); }
static __device__ inline float tanh_fast(float x) {
  return 1.f - 2.f / (1.f + __expf(2.f * x));      // safe at +/-inf
}
static __device__ inline bf16x8 ubf(u32x4 v) {
  union { u32x4 u; bf16x8 b; } c; c.u = v; return c.b;
}

// --- 1. weight conversion (LDS tile transpose, coalesced both sides) -------
__global__ __launch_bounds__(256) void build_wcat(
    const float* __restrict__ Wi, const float* __restrict__ Wh,
    unsigned short* __restrict__ WcatT) {
  __shared__ float tile[64][65];
  int ct = blockIdx.x & 31, kt = blockIdx.x >> 5;    // 32 c-tiles x 12 k-tiles
  int tc = threadIdx.x & 63, tr = threadIdx.x >> 6;
  int c0 = ct * 64, k0 = kt * 64;
#pragma unroll
  for (int i = 0; i < 16; ++i) {
    int r = tr * 16 + i, k = k0 + r;
    float v = (k < EE) ? Wi[(size_t)k * 2048 + c0 + tc]
                       : Wh[(size_t)(k - EE) * 2048 + c0 + tc];
    tile[r][tc] = v;
  }
  __syncthreads();
#pragma unroll
  for (int i = 0; i < 16; ++i) {
    int cL = tr * 16 + i;
    WcatT[(size_t)(c0 + cL) * KCAT + k0 + tc] = (unsigned short)f2bf(tile[tc][cL]);
  }
}

__global__ __launch_bounds__(256) void build_wout(
    const float* __restrict__ Wout, unsigned short* __restrict__ WoutT) {
  __shared__ float tile[64][65];
  int ct = blockIdx.x & 1, kt = blockIdx.x >> 1;     // 2 c-tiles x 8 k-tiles
  int tc = threadIdx.x & 63, tr = threadIdx.x >> 6;
  int c0 = ct * 64, k0 = kt * 64;
#pragma unroll
  for (int i = 0; i < 16; ++i) {
    int r = tr * 16 + i;
    tile[r][tc] = Wout[(size_t)(k0 + r) * KK + c0 + tc];
  }
  __syncthreads();
#pragma unroll
  for (int i = 0; i < 16; ++i) {
    int cL = tr * 16 + i;
    WoutT[(size_t)(c0 + cL) * HH + k0 + tc] = (unsigned short)f2bf(tile[tc][cL]);
  }
}

// --- 2. embedding ----------------------------------------------------------
__global__ __launch_bounds__(256) void embed_kernel(
    const int* __restrict__ wx, const int* __restrict__ cx,
    const float* __restrict__ we, const float* __restrict__ ce,
    unsigned short* __restrict__ x) {
  int bid = blockIdx.x;             // t*64 + b
  int t = bid >> 6, b = bid & 63;
  int e = threadIdx.x;              // 0..255
  int w = wx[b * T_LEN + t];
  float v = we[(size_t)w * EE + e];
  const int* cp = cx + ((size_t)(b * T_LEN + t)) * 8;
  float s = 0.f;
#pragma unroll
  for (int l = 0; l < 8; ++l) s += ce[(size_t)cp[l] * EE + e];
  v += s * 0.125f;
  x[(size_t)bid * EE + e] = (unsigned short)f2bf(v);
}

// --- 3. flag reset: 64 lstm flags + 256 em flags ---------------------------
__global__ void zero_flags(unsigned int* __restrict__ f) {
  int i = threadIdx.x;
  if (i < 320) {
    unsigned z = 0u;
    asm volatile("global_store_dword %0, %1, off sc1"
                 :: "v"(f + i), "v"(z) : "memory");
  }
}

// --- 4. fused persistent kernel ---------------------------------------------
#define SBAR __builtin_amdgcn_sched_barrier(0)
#define WAITV(N) do { asm volatile("s_waitcnt vmcnt(" #N ")" ::: "memory"); SBAR; } while (0)
#define LDN(dst, ptr, OFF) \
  asm volatile("global_load_dwordx4 %0, %1, off offset:" OFF \
               : "=v"(dst) : "v"(ptr) : "memory")

#define ISSUE_X(B, P) do { \
  LDN(B[0],P,"0");   LDN(B[1],P,"32");  LDN(B[2],P,"64");  LDN(B[3],P,"96"); \
  LDN(B[4],P,"128"); LDN(B[5],P,"160"); LDN(B[6],P,"192"); LDN(B[7],P,"224"); \
  LDN(B[8],P,"256"); LDN(B[9],P,"288"); LDN(B[10],P,"320"); LDN(B[11],P,"352"); \
  LDN(B[12],P,"384"); LDN(B[13],P,"416"); LDN(B[14],P,"448"); LDN(B[15],P,"480"); } while (0)
#define ISSUE_H1(B, P) do { \
  LDN(B[0],P,"512"); LDN(B[1],P,"544"); LDN(B[2],P,"576"); LDN(B[3],P,"608"); \
  LDN(B[4],P,"640"); LDN(B[5],P,"672"); LDN(B[6],P,"704"); LDN(B[7],P,"736"); \
  LDN(B[8],P,"768"); LDN(B[9],P,"800"); LDN(B[10],P,"832"); LDN(B[11],P,"864"); \
  LDN(B[12],P,"896"); LDN(B[13],P,"928"); LDN(B[14],P,"960"); LDN(B[15],P,"992"); } while (0)

#define GATES_STORE(T) do { \
    bool mk = ((int)wxv) > 0; \
    _Pragma("unroll") \
    for (int r = 0; r < 4; ++r) { \
      float zi = acc[r], zf = acc[4 + r], zg = acc[8 + r], zo = acc[12 + r]; \
      float cn = sigm(zf) * cst[r] + sigm(zi) * tanh_fast(zg); \
      float hn = sigm(zo) * tanh_fast(cn); \
      if (mk) { cst[r] = cn; hst[r] = hn; } \
    } \
    u32x2 ph; \
    ph[0] = f2bf(hst[0]) | (f2bf(hst[1]) << 16); \
    ph[1] = f2bf(hst[2]) | (f2bf(hst[3]) << 16); \
    asm volatile("global_store_dwordx2 %0, %1, off sc1" \
                 :: "v"(hstore + (size_t)(T) * 65536), "v"(ph) : "memory"); \
  } while (0)

__global__ __launch_bounds__(128, 1) void fused_kernel(
    const unsigned short* __restrict__ x,      // [T][64][256] bf16
    unsigned short* __restrict__ hs,           // [256][64][512] bf16 (slot t = h[t+1])
    const unsigned short* __restrict__ WcatT,  // [2048][768] bf16
    const unsigned short* __restrict__ WoutT,  // [128][512] bf16
    const float* __restrict__ bias,            // [2048]
    const float* __restrict__ bout,            // [128]
    const float* __restrict__ trans,           // [128][128]
    const int* __restrict__ wx,                // [64][256]
    const int* __restrict__ y,                 // [64][257]
    float* __restrict__ em,                    // [16384][128] f32
    unsigned int* __restrict__ flags,          // [64] lstm flags
    unsigned int* __restrict__ emflag,         // [256] em flags
    float* __restrict__ out) {                 // [64]
  __shared__ float s_tl[KK][129];
  __shared__ float s_El[KK][129];
  __shared__ float s_p[KK];
  __shared__ float s_red[16];

  const int bid = blockIdx.x;
  const int tid = threadIdx.x;
  const int wave = tid >> 6, lane = tid & 63;

  if (bid < 64) {
    // ================= LSTM role (r13 verbatim) =================
    const int bhalf = wave;
    const int hi = lane >> 5;
    const int batch = bhalf * 32 + (lane & 31);
    const int u0 = bid * 8;
    const int rr = lane & 31;
    const int wcol = (rr >> 3) * HH + u0 + (rr & 7);

    bf16x8 wreg[48];
#pragma unroll
    for (int kf = 0; kf < 48; ++kf)
      wreg[kf] = *(const bf16x8*)(WcatT + (size_t)wcol * KCAT + kf * 16 + hi * 8);

    float bv[16];
#pragma unroll
    for (int q = 0; q < 4; ++q)
#pragma unroll
      for (int r = 0; r < 4; ++r)
        bv[q * 4 + r] = bias[q * HH + u0 + 4 * hi + r];

    const char* xlane  = (const char*)x  + ((size_t)batch * EE + hi * 8) * 2;
    const char* hread  = (const char*)hs + ((size_t)batch * HH + hi * 8) * 2;
    char*       hstore = (char*)hs + ((size_t)batch * HH + u0 + 4 * hi) * 2;
    const int*  wxp    = wx + batch * T_LEN;

    float cst[4] = {0.f, 0.f, 0.f, 0.f};
    float hst[4] = {0.f, 0.f, 0.f, 0.f};
    u32x4 bufX[16], bufH[16];
    unsigned wxv;
    f32x16 acc;

    // ---- t = 0 ----
    ISSUE_X(bufX, xlane);
    asm volatile("global_load_dword %0, %1, off" : "=v"(wxv) : "v"(wxp) : "memory");
    WAITV(0);
#pragma unroll
    for (int i = 0; i < 16; ++i) acc[i] = bv[i];
#pragma unroll
    for (int kf = 0; kf < 16; ++kf)
      acc = __builtin_amdgcn_mfma_f32_32x32x16_bf16(wreg[kf], ubf(bufX[kf]), acc, 0, 0, 0);
    GATES_STORE(0);
    WAITV(0);
    __syncthreads();
    if (tid == 0)
      __hip_atomic_store(flags + bid, 1u, __ATOMIC_RELAXED, __HIP_MEMORY_SCOPE_AGENT);

    // ---- t = 1..255 ----
    for (int t = 1; t < T_LEN; ++t) {
      const char* xt = xlane + (size_t)t * 32768;
      const char* hp = hread + (size_t)(t - 1) * 65536;

      ISSUE_X(bufX, xt);
      asm volatile("global_load_dword %0, %1, off" : "=v"(wxv) : "v"(wxp + t) : "memory");
      {
        unsigned v;
        do {
          asm volatile("global_load_dword %0, %1, off sc1\n\ts_waitcnt vmcnt(0)"
                       : "=v"(v) : "v"(flags + lane) : "memory");
        } while (!__all((int)(v >= (unsigned)t)));
        SBAR;
      }
      ISSUE_X(bufH, hp);                       // h chunk 0 (plain, L2-shared)
#pragma unroll
      for (int i = 0; i < 16; ++i) acc[i] = bv[i];
#pragma unroll
      for (int kf = 0; kf < 16; ++kf)
        acc = __builtin_amdgcn_mfma_f32_32x32x16_bf16(wreg[kf], ubf(bufX[kf]), acc, 0, 0, 0);
      SBAR;
      ISSUE_H1(bufX, hp);                      // h chunk 1 reuses x buffer
      WAITV(16);
#pragma unroll
      for (int kf = 0; kf < 16; ++kf)
        acc = __builtin_amdgcn_mfma_f32_32x32x16_bf16(wreg[16 + kf], ubf(bufH[kf]), acc, 0, 0, 0);
      WAITV(0);
#pragma unroll
      for (int kf = 0; kf < 16; ++kf)
        acc = __builtin_amdgcn_mfma_f32_32x32x16_bf16(wreg[32 + kf], ubf(bufX[kf]), acc, 0, 0, 0);
      GATES_STORE(t);
      WAITV(0);
      __syncthreads();
      if (tid == 0)
        __hip_atomic_store(flags + bid, (unsigned)(t + 1),
                           __ATOMIC_RELAXED, __HIP_MEMORY_SCOPE_AGENT);
    }
  } else if (bid < 72) {
    // ================= EM role: t = (bid-64) + 8*i =================
    const int et0 = bid - 64;
    const int arow = lane & 15, kg4 = (lane >> 4) * 8;
    for (int i = 0; i < 32; ++i) {
      const int t = et0 + 8 * i;
      {
        unsigned v; int it = 0;
        for (;;) {
          asm volatile("global_load_dword %0, %1, off sc1\n\ts_waitcnt vmcnt(0)"
                       : "=v"(v) : "v"(flags + lane) : "memory");
          if (__all((int)(v >= (unsigned)(t + 1)))) break;
          if (++it >= (1 << 17)) break;        // fail visibly, never hang
          __builtin_amdgcn_s_sleep(2);         // backoff: slack-rich poll
        }
        SBAR;
      }
      const unsigned short* A0 = hs + ((size_t)t * BB + wave * 32 + arow) * HH + kg4;
      f32x4 acc2[2][8];
#pragma unroll
      for (int mt = 0; mt < 2; ++mt)
#pragma unroll
        for (int nt = 0; nt < 8; ++nt) acc2[mt][nt] = (f32x4){0.f, 0.f, 0.f, 0.f};
#pragma unroll
      for (int ks = 0; ks < 16; ++ks) {
        bf16x8 a0 = *(const bf16x8*)(A0 + ks * 32);
        bf16x8 a1 = *(const bf16x8*)(A0 + 16 * HH + ks * 32);
#pragma unroll
        for (int nt = 0; nt < 8; ++nt) {
          bf16x8 bf = *(const bf16x8*)(WoutT + (size_t)(nt * 16 + arow) * HH + kg4 + ks * 32);
          acc2[0][nt] = __builtin_amdgcn_mfma_f32_16x16x32_bf16(a0, bf, acc2[0][nt], 0, 0, 0);
          acc2[1][nt] = __builtin_amdgcn_mfma_f32_16x16x32_bf16(a1, bf, acc2[1][nt], 0, 0, 0);
        }
      }
      // store em[t] (no mask: masked-off entries are never read)
#pragma unroll
      for (int nt = 0; nt < 8; ++nt) {
        int n = nt * 16 + arow;
        float bo = bout[n];
#pragma unroll
        for (int mt = 0; mt < 2; ++mt)
#pragma unroll
          for (int r = 0; r < 4; ++r) {
            int row = t * BB + wave * 32 + mt * 16 + (lane >> 4) * 4 + r;
            float val = acc2[mt][nt][r] + bo;
            asm volatile("global_store_dword %0, %1, off sc1"
                         :: "v"(em + (size_t)row * KK + n), "v"(val) : "memory");
          }
      }
      WAITV(0);
      __syncthreads();
      if (tid == 0)
        __hip_atomic_store(emflag + t, 1u, __ATOMIC_RELAXED, __HIP_MEMORY_SCOPE_AGENT);
    }
  } else {
    // ================= CRF role: b = bid - 72 =================
    const int b = bid - 72;
    const int k = tid;                         // 0..127
    for (int i2 = tid; i2 < KK * KK; i2 += 128) {
      float v = trans[i2];
      s_tl[i2 >> 7][i2 & 127] = v;
      s_El[i2 >> 7][i2 & 127] = __expf(v);     // exp(-1e4) = 0
    }
    __syncthreads();
    float sck = (k == 1) ? 0.f : -10000.f;
    float msc = 0.f;

    for (int t = 0; t < T_LEN; ++t) {
      if (wx[b * T_LEN + t] <= 0) continue;    // block-uniform
      {
        unsigned v; int it = 0;
        for (;;) {
          asm volatile("global_load_dword %0, %1, off sc1\n\ts_waitcnt vmcnt(0)"
                       : "=v"(v) : "v"(emflag + t) : "memory");
          if (v) break;
          if (++it >= (1 << 17)) break;        // fail visibly, never hang
          __builtin_amdgcn_s_sleep(2);         // backoff: slack-rich poll
        }
        SBAR;
      }
      s_p[k] = __expf(sck - msc);
      __syncthreads();
      float S = 0.f;
#pragma unroll
      for (int j = 0; j < KK; ++j) S += s_El[k][j] * s_p[j];
      float ns = em[((size_t)t * BB + b) * KK + k] + msc + __logf(S);
      sck = ns;
      float m = ns;
#pragma unroll
      for (int off = 32; off; off >>= 1) m = fmaxf(m, __shfl_xor(m, off));
      if (lane == 0) s_red[8 + wave] = m;
      __syncthreads();                         // also guards s_p reuse next step
      msc = fmaxf(s_red[8], s_red[9]);
    }

    // gold score (all needed em[t] already flagged during the loop)
    float term = 0.f, cnt = 0.f;
#pragma unroll
    for (int rep = 0; rep < 2; ++rep) {
      int tt = tid + rep * 128;
      int yp = y[b * 257 + tt], yn = y[b * 257 + tt + 1];
      if (wx[b * T_LEN + tt] > 0) {
        term += em[((size_t)tt * BB + b) * KK + yn] + s_tl[yn][yp];
        cnt += 1.f;
      }
    }
#pragma unroll
    for (int off = 32; off; off >>= 1) {
      term += __shfl_xor(term, off);
      cnt += __shfl_xor(cnt, off);
    }
    if (lane == 0) { s_red[wave] = term; s_red[2 + wave] = cnt; }
    __syncthreads();
    float gold = s_red[0] + s_red[1];
    int len = (int)(s_red[2] + s_red[3] + 0.5f);

    // Z = LSE_k(sc[k] + trans[EOS][k])
    float v = sck + s_tl[2][k];
    float mz = v;
#pragma unroll
    for (int off = 32; off; off >>= 1) mz = fmaxf(mz, __shfl_xor(mz, off));
    if (lane == 0) s_red[4 + wave] = mz;
    __syncthreads();
    mz = fmaxf(s_red[4], s_red[5]);
    float e = __expf(v - mz);
#pragma unroll
    for (int off = 32; off; off >>= 1) e += __shfl_xor(e, off);
    if (lane == 0) s_red[6 + wave] = e;
    __syncthreads();
    if (tid == 0) {
      float Z = mz + __logf(s_red[6] + s_red[7]);
      int last_tag = y[b * 257 + len];
      out[b] = Z - (gold + s_tl[2][last_tag]);
    }
  }
}

// ---------------------------------------------------------------------------
extern "C" void kernel_launch(void* const* d_in, const int* in_sizes, int n_in,
                              void* d_out, int out_size, void* d_ws, size_t ws_size,
                              hipStream_t stream) {
  const int*   cx    = (const int*)d_in[0];
  const int*   wx    = (const int*)d_in[1];
  const int*   y     = (const int*)d_in[2];
  const float* ce    = (const float*)d_in[3];
  const float* we    = (const float*)d_in[4];
  const float* Wi    = (const float*)d_in[5];
  const float* Wh    = (const float*)d_in[6];
  const float* bias  = (const float*)d_in[7];
  const float* Wout  = (const float*)d_in[8];
  const float* bout  = (const float*)d_in[9];
  const float* trans = (const float*)d_in[10];
  float* out = (float*)d_out;

  char* ws = (char*)d_ws;
  // ws layout (16B aligned), ~37 MB
  unsigned short* WcatT = (unsigned short*)(ws + 0);          //  3,145,728
  unsigned short* WoutT = (unsigned short*)(ws + 3145728);    //    131,072
  unsigned short* x     = (unsigned short*)(ws + 3276800);    //  8,388,608
  unsigned short* hs    = (unsigned short*)(ws + 11665408);   // 16,777,216
  unsigned int*   flags = (unsigned int*)(ws + 28442624);     //  64 dwords
  unsigned int*   emflag= (unsigned int*)(ws + 28442880);     // 256 dwords
  float*          em    = (float*)(ws + 28444672);            //  8,388,608

  build_wcat<<<384, 256, 0, stream>>>(Wi, Wh, WcatT);
  build_wout<<<16, 256, 0, stream>>>(Wout, WoutT);
  embed_kernel<<<T_LEN * BB, 256, 0, stream>>>(wx, cx, we, ce, x);
  zero_flags<<<1, 320, 0, stream>>>(flags);
  fused_kernel<<<136, 128, 0, stream>>>(x, hs, WcatT, WoutT, bias, bout, trans,
                                        wx, y, em, flags, emflag, out);
}